// Round 2
// baseline (339.479 us; speedup 1.0000x reference)
//
#include <hip/hip_runtime.h>
#include <hip/hip_fp16.h>

#define MUL 16
#define NPAIR 136   // u<=v pairs
#define BLK 512

// ---------------------------------------------------------------------------
// Preprocessing: fold symmetric pairs + normalization constants into a
// weight stream laid out for ds_read_b128:
//   ws[p*80 + 0*16 + w] = f000   (A000 * (w000[uv]+w000[vu]))
//   ws[p*80 + 1*16 + w] = f110
//   ws[p*80 + 2*16 + w] = f112   (A112 * C1 folded in; t4 carries sqrt3 factors)
//   ws[p*80 + 3*16 + w] = f101uv
//   ws[p*80 + 4*16 + w] = f101vu
// ---------------------------------------------------------------------------
__global__ void prep_weights(const float* __restrict__ w000,
                             const float* __restrict__ w101,
                             const float* __restrict__ w110,
                             const float* __restrict__ w112,
                             float* __restrict__ ws) {
    int idx = blockIdx.x * blockDim.x + threadIdx.x;
    if (idx >= NPAIR * MUL) return;
    int p = idx / MUL, w = idx % MUL;
    int u = 0, rem = p;
    while (rem >= MUL - u) { rem -= MUL - u; ++u; }
    int v = u + rem;

    const float A000   = 0.044194173824159216f;   // sqrt(1/(2*16*16))
    const float A110   = 0.025515518153991442f;   // A000/sqrt(3)
    const float A101   = 0.0625f;                 // sqrt(3/256)/sqrt(3)
    const float A112C1 = 0.044194173824159216f;   // A112 / sqrt(10) == A000

    int uv = (u * MUL + v) * MUL + w;
    int vu = (v * MUL + u) * MUL + w;
    float f000, f110, f112, fuv, fvu;
    if (u == v) {
        f000 = A000   * w000[uv];
        f110 = A110   * w110[uv];
        f112 = A112C1 * w112[uv];
        fuv  = A101   * w101[uv];
        fvu  = 0.f;
    } else {
        f000 = A000   * (w000[uv] + w000[vu]);
        f110 = A110   * (w110[uv] + w110[vu]);
        f112 = A112C1 * (w112[uv] + w112[vu]);
        fuv  = A101   * w101[uv];
        fvu  = A101   * w101[vu];
    }
    float* o = ws + p * 80;
    o[w]      = f000;
    o[16 + w] = f110;
    o[32 + w] = f112;
    o[48 + w] = fuv;
    o[64 + w] = fvu;
}

// ---------------------------------------------------------------------------
// Main kernel: 512 threads/block (one node/thread), 1 block/CU.
// x staged in LDS as fp16 (row stride 66 halves = 33 dwords, odd -> <=2-way
// bank aliasing = free). Weights staged in LDS fp32, read as ds_read_b128
// with compile-time offsets (all-lane broadcast, conflict-free).
// ---------------------------------------------------------------------------
__launch_bounds__(BLK, 2)
__global__ void tsq_kernel(const float* __restrict__ feats,
                           const float* __restrict__ msgs,
                           const float* __restrict__ wstream,
                           float* __restrict__ out) {
    __shared__ __half xh[BLK * 66];          // 67584 B
    __shared__ float  wsh[NPAIR * 80];       // 43520 B
    const int tid = threadIdx.x;
    const long long blockNode = (long long)blockIdx.x * BLK;

    // ---- stage weights (broadcast-reused) into LDS, coalesced float4 ----
    {
        const float4* w4 = (const float4*)wstream;
        float4* s4 = (float4*)wsh;
        for (int i = tid; i < NPAIR * 20; i += BLK) s4[i] = w4[i];
    }
    // ---- stage x = feats+msgs into LDS as fp16, coalesced float4 loads ----
    {
        const float4* f4 = (const float4*)(feats + blockNode * 64);
        const float4* m4 = (const float4*)(msgs + blockNode * 64);
        __half2* xh2 = (__half2*)xh;
#pragma unroll
        for (int k = 0; k < 16; ++k) {
            int i = k * BLK + tid;
            float4 a = f4[i];
            float4 b = m4[i];
            int fi   = i * 4;
            int node = fi >> 6;
            int off  = fi & 63;
            int h2   = node * 33 + (off >> 1);
            xh2[h2]     = __floats2half2_rn(a.x + b.x, a.y + b.y);
            xh2[h2 + 1] = __floats2half2_rn(a.z + b.z, a.w + b.w);
        }
    }
    __syncthreads();

    float acc0[16];
    float acc1[16][3];
    float acc2[16][5];
#pragma unroll
    for (int w = 0; w < 16; ++w) {
        acc0[w] = 0.f;
#pragma unroll
        for (int k = 0; k < 3; ++k) acc1[w][k] = 0.f;
#pragma unroll
        for (int k = 0; k < 5; ++k) acc2[w][k] = 0.f;
    }

    const __half* row = &xh[tid * 66];
    const float SQ3  = 1.7320508075688772f;   // sqrt(3)
    const float ISQ3 = 0.5773502691896258f;   // 1/sqrt(3)

    const float* wp = wsh;
    for (int u = 0; u < MUL; ++u) {
        float xu0  = __half2float(row[u]);
        float xu1a = __half2float(row[16 + 3 * u]);
        float xu1b = __half2float(row[16 + 3 * u + 1]);
        float xu1c = __half2float(row[16 + 3 * u + 2]);
        for (int v = u; v < MUL; ++v) {
            float xv0  = __half2float(row[v]);
            float xv1a = __half2float(row[16 + 3 * v]);
            float xv1b = __half2float(row[16 + 3 * v + 1]);
            float xv1c = __half2float(row[16 + 3 * v + 2]);

            float o00 = xu1a * xv1a, o01 = xu1a * xv1b, o02 = xu1a * xv1c;
            float o10 = xu1b * xv1a, o11 = xu1b * xv1b, o12 = xu1b * xv1c;
            float o20 = xu1c * xv1a, o21 = xu1c * xv1b, o22 = xu1c * xv1c;
            float s0p = xu0 * xv0;
            float s1p = (o00 + o11) + o22;
            float t0 = o01 + o10;
            float t1 = o02 + o20;
            float t2 = o12 + o21;
            float t3 = o00 - o11;
            float t4 = SQ3 * o22 - ISQ3 * s1p;   // (2*o22-o00-o11)/sqrt(3)
            float p0 = xu1a * xv0, p1 = xu1b * xv0, p2 = xu1c * xv0;
            float q0 = xv1a * xu0, q1 = xv1b * xu0, q2 = xv1c * xu0;

#pragma unroll
            for (int wq = 0; wq < 4; ++wq) {
                float4 f000q = *(const float4*)(wp +      wq * 4);
                float4 f110q = *(const float4*)(wp + 16 + wq * 4);
                float4 f112q = *(const float4*)(wp + 32 + wq * 4);
                float4 fuvq  = *(const float4*)(wp + 48 + wq * 4);
                float4 fvuq  = *(const float4*)(wp + 64 + wq * 4);
                const float* f000 = (const float*)&f000q;
                const float* f110 = (const float*)&f110q;
                const float* f112 = (const float*)&f112q;
                const float* fuv  = (const float*)&fuvq;
                const float* fvu  = (const float*)&fvuq;
#pragma unroll
                for (int j = 0; j < 4; ++j) {
                    int w = wq * 4 + j;
                    acc0[w] += f000[j] * s0p + f110[j] * s1p;
                    acc1[w][0] += fuv[j] * p0 + fvu[j] * q0;
                    acc1[w][1] += fuv[j] * p1 + fvu[j] * q1;
                    acc1[w][2] += fuv[j] * p2 + fvu[j] * q2;
                    acc2[w][0] += f112[j] * t0;
                    acc2[w][1] += f112[j] * t1;
                    acc2[w][2] += f112[j] * t2;
                    acc2[w][3] += f112[j] * t3;
                    acc2[w][4] += f112[j] * t4;
                }
            }
            wp += 80;
        }
    }

    // ---- write 144 floats per node as 36 float4 stores ----
    float4* o4 = (float4*)(out + (blockNode + tid) * 144);
#pragma unroll
    for (int j = 0; j < 4; ++j) {
        o4[j] = make_float4(acc0[4 * j], acc0[4 * j + 1],
                            acc0[4 * j + 2], acc0[4 * j + 3]);
    }
#pragma unroll
    for (int j = 0; j < 12; ++j) {
        int e = 4 * j;
        o4[4 + j] = make_float4(acc1[(e + 0) / 3][(e + 0) % 3],
                                acc1[(e + 1) / 3][(e + 1) % 3],
                                acc1[(e + 2) / 3][(e + 2) % 3],
                                acc1[(e + 3) / 3][(e + 3) % 3]);
    }
#pragma unroll
    for (int j = 0; j < 20; ++j) {
        int e = 4 * j;
        o4[16 + j] = make_float4(acc2[(e + 0) / 5][(e + 0) % 5],
                                 acc2[(e + 1) / 5][(e + 1) % 5],
                                 acc2[(e + 2) / 5][(e + 2) % 5],
                                 acc2[(e + 3) / 5][(e + 3) % 5]);
    }
}

extern "C" void kernel_launch(void* const* d_in, const int* in_sizes, int n_in,
                              void* d_out, int out_size, void* d_ws, size_t ws_size,
                              hipStream_t stream) {
    const float* feats = (const float*)d_in[0];
    const float* msgs  = (const float*)d_in[1];
    const float* w000  = (const float*)d_in[2];
    const float* w101  = (const float*)d_in[3];
    const float* w110  = (const float*)d_in[4];
    const float* w112  = (const float*)d_in[5];
    float* ws  = (float*)d_ws;
    float* out = (float*)d_out;

    const int n = in_sizes[0] / (4 * MUL);   // number of nodes (131072)

    prep_weights<<<(NPAIR * MUL + 255) / 256, 256, 0, stream>>>(w000, w101, w110, w112, ws);
    tsq_kernel<<<n / BLK, BLK, 0, stream>>>(feats, msgs, ws, out);
}

// Round 3
// 236.252 us; speedup vs baseline: 1.4369x; 1.4369x over previous
//
#include <hip/hip_runtime.h>

#define MUL 16
#define NPAIR 136          // u<=v pairs
#define BLK 512
#define NPB 256            // nodes per block

// ---------------------------------------------------------------------------
// Preprocessing: fold symmetric pairs + normalization into a stream laid out
// for wave-uniform scalar loads, split by w-half h = w>>3:
//   ws[(p*2+h)*40 + {0..7:f000, 8..15:f110, 16..23:f112, 24..31:fuv, 32..39:fvu}]
// f112 has A112/sqrt(10) folded in (== A000); t4 carries the extra sqrt(3)s.
// ---------------------------------------------------------------------------
__global__ void prep_weights(const float* __restrict__ w000,
                             const float* __restrict__ w101,
                             const float* __restrict__ w110,
                             const float* __restrict__ w112,
                             float* __restrict__ ws) {
    int idx = blockIdx.x * blockDim.x + threadIdx.x;
    if (idx >= NPAIR * MUL) return;
    int p = idx / MUL, w = idx % MUL;
    int u = 0, rem = p;
    while (rem >= MUL - u) { rem -= MUL - u; ++u; }
    int v = u + rem;

    const float A000   = 0.044194173824159216f;   // sqrt(1/(2*16*16))
    const float A110   = 0.025515518153991442f;   // A000/sqrt(3)
    const float A101   = 0.0625f;                 // sqrt(3/256)/sqrt(3)
    const float A112C1 = 0.044194173824159216f;   // A112/sqrt(10) == A000

    int uv = (u * MUL + v) * MUL + w;
    int vu = (v * MUL + u) * MUL + w;
    float f000, f110, f112, fuv, fvu;
    if (u == v) {
        f000 = A000   * w000[uv];
        f110 = A110   * w110[uv];
        f112 = A112C1 * w112[uv];
        fuv  = A101   * w101[uv];
        fvu  = 0.f;
    } else {
        f000 = A000   * (w000[uv] + w000[vu]);
        f110 = A110   * (w110[uv] + w110[vu]);
        f112 = A112C1 * (w112[uv] + w112[vu]);
        fuv  = A101   * w101[uv];
        fvu  = A101   * w101[vu];
    }
    int h = w >> 3, j = w & 7;
    float* o = ws + (p * 2 + h) * 40;
    o[j]      = f000;
    o[8 + j]  = f110;
    o[16 + j] = f112;
    o[24 + j] = fuv;
    o[32 + j] = fvu;
}

// ---------------------------------------------------------------------------
// Main kernel: 512 threads (8 waves). Wave w handles w-half (w&1) of node
// group (w>>1): 256 nodes/block, 2 "w-threads" per node in different waves so
// the weight pointer is wave-uniform -> compiler scalarizes to s_load.
// 72 fp32 accumulators/thread -> fits VGPR budget at 4 waves/SIMD, no AGPRs.
// x staged fp32 in LDS, row stride 65 (2-way bank aliasing = free).
// ---------------------------------------------------------------------------
__launch_bounds__(BLK, 4)
__global__ void tsq_kernel(const float* __restrict__ feats,
                           const float* __restrict__ msgs,
                           const float* __restrict__ wstream,
                           float* __restrict__ out) {
    __shared__ float xsh[NPB * 65];      // 66560 B -> 2 blocks/CU
    const int tid = threadIdx.x;
    const long long blockNode = (long long)blockIdx.x * NPB;

    // ---- stage x = feats + msgs, coalesced float4 ----
    {
        const float4* f4 = (const float4*)(feats + blockNode * 64);
        const float4* m4 = (const float4*)(msgs + blockNode * 64);
#pragma unroll
        for (int k = 0; k < 8; ++k) {
            int i = k * BLK + tid;           // 4096 float4 per block
            float4 a = f4[i];
            float4 b = m4[i];
            int fi   = i * 4;
            int node = fi >> 6;
            int off  = fi & 63;
            float* dst = &xsh[node * 65 + off];
            dst[0] = a.x + b.x; dst[1] = a.y + b.y;
            dst[2] = a.z + b.z; dst[3] = a.w + b.w;
        }
    }
    __syncthreads();

    const int wave = tid >> 6;
    const int lane = tid & 63;
    const int wh   = __builtin_amdgcn_readfirstlane(wave & 1);  // w-half, wave-uniform
    const int nodeLocal = (wave >> 1) * 64 + lane;

    float acc0[8];
    float acc1[8][3];
    float acc2[8][5];
#pragma unroll
    for (int j = 0; j < 8; ++j) {
        acc0[j] = 0.f;
#pragma unroll
        for (int k = 0; k < 3; ++k) acc1[j][k] = 0.f;
#pragma unroll
        for (int k = 0; k < 5; ++k) acc2[j][k] = 0.f;
    }

    const float* row = &xsh[nodeLocal * 65];
    const float SQ3  = 1.7320508075688772f;   // sqrt(3)
    const float ISQ3 = 0.5773502691896258f;   // 1/sqrt(3)

    const float* wp = wstream + wh * 40;
    for (int u = 0; u < MUL; ++u) {
        float xu0  = row[u];
        float xu1a = row[16 + 3 * u];
        float xu1b = row[16 + 3 * u + 1];
        float xu1c = row[16 + 3 * u + 2];
        for (int v = u; v < MUL; ++v) {
            float xv0  = row[v];
            float xv1a = row[16 + 3 * v];
            float xv1b = row[16 + 3 * v + 1];
            float xv1c = row[16 + 3 * v + 2];

            float o00 = xu1a * xv1a, o01 = xu1a * xv1b, o02 = xu1a * xv1c;
            float o10 = xu1b * xv1a, o11 = xu1b * xv1b, o12 = xu1b * xv1c;
            float o20 = xu1c * xv1a, o21 = xu1c * xv1b, o22 = xu1c * xv1c;
            float s0p = xu0 * xv0;
            float s1p = (o00 + o11) + o22;
            float t0 = o01 + o10;
            float t1 = o02 + o20;
            float t2 = o12 + o21;
            float t3 = o00 - o11;
            float t4 = SQ3 * o22 - ISQ3 * s1p;     // (2*o22-o00-o11)/sqrt(3)
            float p0 = xu1a * xv0, p1 = xu1b * xv0, p2 = xu1c * xv0;
            float q0 = xv1a * xu0, q1 = xv1b * xu0, q2 = xv1c * xu0;

#pragma unroll
            for (int j = 0; j < 8; ++j) {
                float f000 = wp[j];
                float f110 = wp[8 + j];
                float f112 = wp[16 + j];
                float fuv  = wp[24 + j];
                float fvu  = wp[32 + j];
                acc0[j] += f000 * s0p + f110 * s1p;
                acc1[j][0] += fuv * p0 + fvu * q0;
                acc1[j][1] += fuv * p1 + fvu * q1;
                acc1[j][2] += fuv * p2 + fvu * q2;
                acc2[j][0] += f112 * t0;
                acc2[j][1] += f112 * t1;
                acc2[j][2] += f112 * t2;
                acc2[j][3] += f112 * t3;
                acc2[j][4] += f112 * t4;
            }
            wp += 80;
        }
    }

    // ---- store this thread's w-half: 8 + 24 + 40 floats, all float4 ----
    float* obase = out + (blockNode + nodeLocal) * 144;
    float4* o0 = (float4*)(obase + wh * 8);
    o0[0] = make_float4(acc0[0], acc0[1], acc0[2], acc0[3]);
    o0[1] = make_float4(acc0[4], acc0[5], acc0[6], acc0[7]);

    float4* o1 = (float4*)(obase + 16 + wh * 24);
#pragma unroll
    for (int q = 0; q < 6; ++q) {
        int e = 4 * q;
        o1[q] = make_float4(acc1[(e + 0) / 3][(e + 0) % 3],
                            acc1[(e + 1) / 3][(e + 1) % 3],
                            acc1[(e + 2) / 3][(e + 2) % 3],
                            acc1[(e + 3) / 3][(e + 3) % 3]);
    }

    float4* o2 = (float4*)(obase + 64 + wh * 40);
#pragma unroll
    for (int q = 0; q < 10; ++q) {
        int e = 4 * q;
        o2[q] = make_float4(acc2[(e + 0) / 5][(e + 0) % 5],
                            acc2[(e + 1) / 5][(e + 1) % 5],
                            acc2[(e + 2) / 5][(e + 2) % 5],
                            acc2[(e + 3) / 5][(e + 3) % 5]);
    }
}

extern "C" void kernel_launch(void* const* d_in, const int* in_sizes, int n_in,
                              void* d_out, int out_size, void* d_ws, size_t ws_size,
                              hipStream_t stream) {
    const float* feats = (const float*)d_in[0];
    const float* msgs  = (const float*)d_in[1];
    const float* w000  = (const float*)d_in[2];
    const float* w101  = (const float*)d_in[3];
    const float* w110  = (const float*)d_in[4];
    const float* w112  = (const float*)d_in[5];
    float* ws  = (float*)d_ws;
    float* out = (float*)d_out;

    const int n = in_sizes[0] / (4 * MUL);   // number of nodes (131072)

    prep_weights<<<(NPAIR * MUL + 255) / 256, 256, 0, stream>>>(w000, w101, w110, w112, ws);
    tsq_kernel<<<n / NPB, BLK, 0, stream>>>(feats, msgs, ws, out);
}

// Round 4
// 195.251 us; speedup vs baseline: 1.7387x; 1.2100x over previous
//
#include <hip/hip_runtime.h>

#define MUL 16
#define NPAIR 136
#define NPB 16            // nodes per block
#define FSTR 1960         // feature row stride in bf16 elements (980 dwords == 20 mod 32)
#define NTILE 23          // B fragment tiles: 9 (s) + 9 (pq) + 5 (t)

typedef __bf16 bf16x8 __attribute__((ext_vector_type(8)));
typedef __bf16 bf16x4 __attribute__((ext_vector_type(4)));
typedef float  f32x4  __attribute__((ext_vector_type(4)));

// ---------------------------------------------------------------------------
// Prep: fold symmetric pairs + normalization, emit bf16 B-operand fragments
// for mfma_f32_16x16x32_bf16. B[k][n]: lane = (k_in_tile>>3)*16 + n, j = k&7.
// Tile map: s-tiles 0..8 (K rows 2p->f000, 2p+1->f110, K=272 pad 288),
//           pq-tiles 9..17 (2p->fuv, 2p+1->fvu),
//           t-tiles 18..22 (row p -> f112, K=136 pad 160).
// Pad rows are zeroed by the hipMemsetAsync in kernel_launch.
// ---------------------------------------------------------------------------
__global__ void prep_weights(const float* __restrict__ w000,
                             const float* __restrict__ w101,
                             const float* __restrict__ w110,
                             const float* __restrict__ w112,
                             __bf16* __restrict__ wt) {
    int idx = blockIdx.x * blockDim.x + threadIdx.x;
    if (idx >= NPAIR * MUL) return;
    int p = idx / MUL, w = idx % MUL;
    int u = 0, rem = p;
    while (rem >= MUL - u) { rem -= MUL - u; ++u; }
    int v = u + rem;

    const float A000   = 0.044194173824159216f;   // sqrt(1/(2*16*16))
    const float A110   = 0.025515518153991442f;   // A000/sqrt(3)
    const float A101   = 0.0625f;
    const float A112C1 = 0.044194173824159216f;   // A112/sqrt(10)

    int uv = (u * MUL + v) * MUL + w;
    int vu = (v * MUL + u) * MUL + w;
    float f000, f110, f112, fuv, fvu;
    if (u == v) {
        f000 = A000   * w000[uv];
        f110 = A110   * w110[uv];
        f112 = A112C1 * w112[uv];
        fuv  = A101   * w101[uv];
        fvu  = 0.f;
    } else {
        f000 = A000   * (w000[uv] + w000[vu]);
        f110 = A110   * (w110[uv] + w110[vu]);
        f112 = A112C1 * (w112[uv] + w112[vu]);
        fuv  = A101   * w101[uv];
        fvu  = A101   * w101[vu];
    }

    auto put = [&](int T, int kit, float val) {
        int lanei = ((kit >> 3) << 4) + w;
        wt[(T * 64 + lanei) * 8 + (kit & 7)] = (__bf16)val;
    };
    int k = 2 * p, k2 = 2 * p + 1;
    put(k >> 5,        k & 31,  f000);
    put(k2 >> 5,       k2 & 31, f110);
    put(9 + (k >> 5),  k & 31,  fuv);
    put(9 + (k2 >> 5), k2 & 31, fvu);
    put(18 + (p >> 5), p & 31,  f112);
}

// ---------------------------------------------------------------------------
// Main: 256 threads / 16 nodes per block.
// Phase 0: stage x as per-v quads (x0v,x1va,x1vb,x1vc) in LDS; build pair
//          table; zero feature pad chunks (NaN x 0 hazard).
// Phase 1: 544 tasks (34 pair-quads x 16 nodes): compute 14 features/pair in
//          fp32, pack bf16, vector-store into MFMA-A layout in LDS.
// Phase 2: 4 waves x {9..19} mfma_f32_16x16x32_bf16, scatter fp32 stores.
// ---------------------------------------------------------------------------
__launch_bounds__(256, 2)
__global__ void tsq_kernel(const float* __restrict__ feats,
                           const float* __restrict__ msgs,
                           const __bf16* __restrict__ wtiles,
                           float* __restrict__ out) {
    __shared__ __bf16 feat[NPB * FSTR];   // 62720 B
    __shared__ float  xq[NPB * 68];       // 4352 B
    __shared__ int    UV[NPAIR];          // 544 B

    const int tid = threadIdx.x;
    const long long blockNode = (long long)blockIdx.x * NPB;

    // ---- pair table ----
    if (tid < NPAIR) {
        int u = 0, rem = tid;
        while (rem >= MUL - u) { rem -= MUL - u; ++u; }
        UV[tid] = u | ((u + rem) << 16);
    }
    // ---- x staging: thread (nd, v) builds quad (x0v, x1v[0..2]) ----
    {
        int nd = tid >> 4, v = tid & 15;
        const float* fp = feats + (blockNode + nd) * 64;
        const float* mp = msgs  + (blockNode + nd) * 64;
        float4 q;
        q.x = fp[v]          + mp[v];
        q.y = fp[16 + 3 * v] + mp[16 + 3 * v];
        q.z = fp[17 + 3 * v] + mp[17 + 3 * v];
        q.w = fp[18 + 3 * v] + mp[18 + 3 * v];
        *(float4*)&xq[nd * 68 + 4 * v] = q;
    }
    // ---- zero K-pad chunks of the feature rows ----
    {
        static const int PADOFF[23] = {
            272, 280, 560, 568, 848, 856, 1136, 1144,
            1288, 1296, 1304, 1448, 1456, 1464, 1608, 1616, 1624,
            1768, 1776, 1784, 1928, 1936, 1944};
        for (int t = tid; t < 512; t += 256) {
            int nd = t >> 5, j = t & 31;
            if (j < 23) {
                bf16x8 z = {};
                *(bf16x8*)&feat[nd * FSTR + PADOFF[j]] = z;
            }
        }
    }
    __syncthreads();

    // ---- phase 1: pair features ----
    const float SQ3  = 1.7320508075688772f;
    const float ISQ3 = 0.5773502691896258f;
    for (int T = tid; T < 544; T += 256) {
        int nd = T & 15, g = T >> 4;       // g in [0,34)
        int p0 = 4 * g;
        float sf[8], pqf[3][8], tf[5][4];
#pragma unroll
        for (int i = 0; i < 4; ++i) {
            int uvp = UV[p0 + i];
            int u = uvp & 0xffff, v = uvp >> 16;
            float4 xu = *(const float4*)&xq[nd * 68 + 4 * u];
            float4 xv = *(const float4*)&xq[nd * 68 + 4 * v];
            float o00 = xu.y * xv.y, o01 = xu.y * xv.z, o02 = xu.y * xv.w;
            float o10 = xu.z * xv.y, o11 = xu.z * xv.z, o12 = xu.z * xv.w;
            float o20 = xu.w * xv.y, o21 = xu.w * xv.z, o22 = xu.w * xv.w;
            float s1p = (o00 + o11) + o22;
            sf[2 * i]     = xu.x * xv.x;
            sf[2 * i + 1] = s1p;
            pqf[0][2 * i] = xu.y * xv.x; pqf[0][2 * i + 1] = xv.y * xu.x;
            pqf[1][2 * i] = xu.z * xv.x; pqf[1][2 * i + 1] = xv.z * xu.x;
            pqf[2][2 * i] = xu.w * xv.x; pqf[2][2 * i + 1] = xv.w * xu.x;
            tf[0][i] = o01 + o10;
            tf[1][i] = o02 + o20;
            tf[2][i] = o12 + o21;
            tf[3][i] = o00 - o11;
            tf[4][i] = SQ3 * o22 - ISQ3 * s1p;
        }
        __bf16* fb = &feat[nd * FSTR];
        bf16x8 sv;
#pragma unroll
        for (int j = 0; j < 8; ++j) sv[j] = (__bf16)sf[j];
        *(bf16x8*)&fb[8 * g] = sv;
#pragma unroll
        for (int kk = 0; kk < 3; ++kk) {
            bf16x8 pv;
#pragma unroll
            for (int j = 0; j < 8; ++j) pv[j] = (__bf16)pqf[kk][j];
            *(bf16x8*)&fb[288 * (kk + 1) + 8 * g] = pv;
        }
#pragma unroll
        for (int kk = 0; kk < 5; ++kk) {
            bf16x4 tv;
#pragma unroll
            for (int j = 0; j < 4; ++j) tv[j] = (__bf16)tf[kk][j];
            *(bf16x4*)&fb[1152 + 160 * kk + 4 * g] = tv;
        }
    }
    __syncthreads();

    // ---- phase 2: MFMA ----
    const int lane = tid & 63;
    const int wid  = __builtin_amdgcn_readfirstlane(tid >> 6);
    const int aRow = lane & 15;        // A row = node
    const int quad = lane >> 4;
    const __bf16* fbase = &feat[aRow * FSTR + quad * 8];
    const bf16x8* wb = (const bf16x8*)wtiles;

    f32x4 accA = {0.f, 0.f, 0.f, 0.f};
    f32x4 accB = {0.f, 0.f, 0.f, 0.f};
    f32x4 accC = {0.f, 0.f, 0.f, 0.f};

    const int w = lane & 15;           // C/D col = output index

    if (wid == 0) {
        // out0 (s-tiles 0..8) + t3, t4 (tiles 18..22)
#pragma unroll
        for (int T = 0; T < 9; ++T)
            accA = __builtin_amdgcn_mfma_f32_16x16x32_bf16(
                *(const bf16x8*)&fbase[32 * T], wb[T * 64 + lane], accA, 0, 0, 0);
#pragma unroll
        for (int T = 0; T < 5; ++T) {
            bf16x8 bt = wb[(18 + T) * 64 + lane];
            accB = __builtin_amdgcn_mfma_f32_16x16x32_bf16(
                *(const bf16x8*)&fbase[1632 + 32 * T], bt, accB, 0, 0, 0);
            accC = __builtin_amdgcn_mfma_f32_16x16x32_bf16(
                *(const bf16x8*)&fbase[1792 + 32 * T], bt, accC, 0, 0, 0);
        }
#pragma unroll
        for (int r = 0; r < 4; ++r) {
            int nd = quad * 4 + r;
            float* ob = out + (blockNode + nd) * 144;
            ob[w]             = accA[r];
            ob[64 + 5 * w + 3] = accB[r];
            ob[64 + 5 * w + 4] = accC[r];
        }
    } else {
        int kk = wid - 1;              // pq component 0..2
#pragma unroll
        for (int T = 0; T < 9; ++T)
            accA = __builtin_amdgcn_mfma_f32_16x16x32_bf16(
                *(const bf16x8*)&fbase[288 * (kk + 1) + 32 * T],
                wb[(9 + T) * 64 + lane], accA, 0, 0, 0);
#pragma unroll
        for (int T = 0; T < 5; ++T)
            accB = __builtin_amdgcn_mfma_f32_16x16x32_bf16(
                *(const bf16x8*)&fbase[1152 + 160 * kk + 32 * T],
                wb[(18 + T) * 64 + lane], accB, 0, 0, 0);
#pragma unroll
        for (int r = 0; r < 4; ++r) {
            int nd = quad * 4 + r;
            float* ob = out + (blockNode + nd) * 144;
            ob[16 + 3 * w + kk] = accA[r];
            ob[64 + 5 * w + kk] = accB[r];
        }
    }
}

extern "C" void kernel_launch(void* const* d_in, const int* in_sizes, int n_in,
                              void* d_out, int out_size, void* d_ws, size_t ws_size,
                              hipStream_t stream) {
    const float* feats = (const float*)d_in[0];
    const float* msgs  = (const float*)d_in[1];
    const float* w000  = (const float*)d_in[2];
    const float* w101  = (const float*)d_in[3];
    const float* w110  = (const float*)d_in[4];
    const float* w112  = (const float*)d_in[5];
    __bf16* wt = (__bf16*)d_ws;
    float* out = (float*)d_out;

    const int n = in_sizes[0] / (4 * MUL);   // 131072 nodes

    hipMemsetAsync(d_ws, 0, NTILE * 64 * 8 * sizeof(__bf16), stream);
    prep_weights<<<(NPAIR * MUL + 255) / 256, 256, 0, stream>>>(w000, w101, w110, w112, wt);
    tsq_kernel<<<n / NPB, 256, 0, stream>>>(feats, msgs, wt, out);
}

// Round 5
// 191.744 us; speedup vs baseline: 1.7705x; 1.0183x over previous
//
#include <hip/hip_runtime.h>

#define MUL 16
#define NPAIR 136
#define NPB 16            // nodes per block
#define SSTR 40           // chunk row stride in bf16 (20 dwords: 4*odd -> spread banks)
#define NTILE 23          // B fragment tiles: 9 (s) + 9 (pq) + 5 (t)

typedef __bf16 bf16x8 __attribute__((ext_vector_type(8)));
typedef __bf16 bf16x2 __attribute__((ext_vector_type(2)));
typedef float  f32x4  __attribute__((ext_vector_type(4)));

// ---------------------------------------------------------------------------
// Prep (single block): zero all B-tiles, then fold symmetric pairs +
// normalization into bf16 B-fragments for mfma_f32_16x16x32_bf16.
// B[k][n]: lane = (k_in_tile>>3)*16 + n, j = k&7.
//   s-tiles 0..8:  k=2P -> f000, k=2P+1 -> f110   (K=272, pad to 288)
//   pq-tiles 9..17: k=2P -> fuv,  k=2P+1 -> fvu
//   t-tiles 18..22: k=P  -> f112                  (K=136, pad to 160)
// ---------------------------------------------------------------------------
__global__ void prep_weights(const float* __restrict__ w000,
                             const float* __restrict__ w101,
                             const float* __restrict__ w110,
                             const float* __restrict__ w112,
                             __bf16* __restrict__ wt) {
    const int tid = threadIdx.x;
    for (int i = tid; i < NTILE * 64; i += 256) {
        bf16x8 z = {};
        ((bf16x8*)wt)[i] = z;
    }
    __syncthreads();

    const float A000   = 0.044194173824159216f;   // sqrt(1/(2*16*16))
    const float A110   = 0.025515518153991442f;   // A000/sqrt(3)
    const float A101   = 0.0625f;
    const float A112C1 = 0.044194173824159216f;   // A112/sqrt(10)

    for (int idx = tid; idx < NPAIR * MUL; idx += 256) {
        int p = idx / MUL, w = idx % MUL;
        int u = 0, rem = p;
        while (rem >= MUL - u) { rem -= MUL - u; ++u; }
        int v = u + rem;

        int uv = (u * MUL + v) * MUL + w;
        int vu = (v * MUL + u) * MUL + w;
        float f000, f110, f112, fuv, fvu;
        if (u == v) {
            f000 = A000   * w000[uv];
            f110 = A110   * w110[uv];
            f112 = A112C1 * w112[uv];
            fuv  = A101   * w101[uv];
            fvu  = 0.f;
        } else {
            f000 = A000   * (w000[uv] + w000[vu]);
            f110 = A110   * (w110[uv] + w110[vu]);
            f112 = A112C1 * (w112[uv] + w112[vu]);
            fuv  = A101   * w101[uv];
            fvu  = A101   * w101[vu];
        }
        auto put = [&](int T, int kit, float val) {
            int lanei = ((kit >> 3) << 4) + w;
            wt[(T * 64 + lanei) * 8 + (kit & 7)] = (__bf16)val;
        };
        int k = 2 * p, k2 = 2 * p + 1;
        put(k >> 5,        k & 31,  f000);
        put(k2 >> 5,       k2 & 31, f110);
        put(9 + (k >> 5),  k & 31,  fuv);
        put(9 + (k2 >> 5), k2 & 31, fvu);
        put(18 + (p >> 5), p & 31,  f112);
    }
}

// ---------------------------------------------------------------------------
// Main: 256 threads / 16 nodes / block, 4 blocks/CU (28 KB LDS).
// K-chunked double-buffered pipeline: per chunk, thread (pair,node) computes
// the tile's features fp32->bf16 into a small LDS chunk buffer; 1 barrier;
// each wave issues its MFMA(s). Roles: wid0 = out0 (s) + t3,t4; wid kk=1..3
// = out1 comp kk-1 (pq) + out2 comp kk-1 (t).
// ---------------------------------------------------------------------------
__launch_bounds__(256, 4)
__global__ void tsq_kernel(const float* __restrict__ feats,
                           const float* __restrict__ msgs,
                           const __bf16* __restrict__ wtiles,
                           float* __restrict__ out) {
    __shared__ float  xq[NPB * 68];                 // 4352 B
    __shared__ int    UVs[NPAIR];                   // 544 B
    __shared__ __bf16 sbuf[2][NPB * SSTR];          // 2560 B
    __shared__ __bf16 pqbuf[2][3][NPB * SSTR];      // 7680 B
    __shared__ __bf16 tbuf[2][5][NPB * SSTR];       // 12800 B

    const int tid = threadIdx.x;
    const long long blockNode = (long long)blockIdx.x * NPB;

    // ---- pair table ----
    if (tid < NPAIR) {
        int u = 0, rem = tid;
        while (rem >= MUL - u) { rem -= MUL - u; ++u; }
        UVs[tid] = u | ((u + rem) << 16);
    }
    // ---- x staging: thread (nd, v) builds quad (x0v, x1v[0..2]) ----
    {
        int nd = tid >> 4, v = tid & 15;
        const float* fp = feats + (blockNode + nd) * 64;
        const float* mp = msgs  + (blockNode + nd) * 64;
        float4 qd;
        qd.x = fp[v]          + mp[v];
        qd.y = fp[16 + 3 * v] + mp[16 + 3 * v];
        qd.z = fp[17 + 3 * v] + mp[17 + 3 * v];
        qd.w = fp[18 + 3 * v] + mp[18 + 3 * v];
        *(float4*)&xq[nd * 68 + 4 * v] = qd;
    }
    __syncthreads();

    const float SQ3  = 1.7320508075688772f;
    const float ISQ3 = 0.5773502691896258f;
    const int nd = tid & 15, pi = tid >> 4;

    // chunk c covers pairs 16c..16c+15 (s + pq families, 2 k's per pair)
    auto computeSP = [&](int c, int b) {
        int P = 16 * c + pi;
        int o = nd * SSTR + 2 * pi;
        if (P < NPAIR) {
            int uvp = UVs[P];
            int u = uvp & 0xffff, v = uvp >> 16;
            float4 xu = *(const float4*)&xq[nd * 68 + 4 * u];
            float4 xv = *(const float4*)&xq[nd * 68 + 4 * v];
            float s0 = xu.x * xv.x;
            float s1 = xu.y * xv.y + xu.z * xv.z + xu.w * xv.w;
            *(bf16x2*)&sbuf[b][o]      = (bf16x2){(__bf16)s0, (__bf16)s1};
            *(bf16x2*)&pqbuf[b][0][o]  = (bf16x2){(__bf16)(xu.y * xv.x), (__bf16)(xv.y * xu.x)};
            *(bf16x2*)&pqbuf[b][1][o]  = (bf16x2){(__bf16)(xu.z * xv.x), (__bf16)(xv.z * xu.x)};
            *(bf16x2*)&pqbuf[b][2][o]  = (bf16x2){(__bf16)(xu.w * xv.x), (__bf16)(xv.w * xu.x)};
        } else {
            bf16x2 z = {};
            *(bf16x2*)&sbuf[b][o]     = z;
            *(bf16x2*)&pqbuf[b][0][o] = z;
            *(bf16x2*)&pqbuf[b][1][o] = z;
            *(bf16x2*)&pqbuf[b][2][o] = z;
        }
    };

    // chunk c covers pairs 32c..32c+31 (t family, 1 k per pair); thread does 2
    auto computeT = [&](int c, int b) {
        float tf[5][2];
#pragma unroll
        for (int e = 0; e < 2; ++e) {
            int P = 32 * c + 2 * pi + e;
            if (P < NPAIR) {
                int uvp = UVs[P];
                int u = uvp & 0xffff, v = uvp >> 16;
                float4 xu = *(const float4*)&xq[nd * 68 + 4 * u];
                float4 xv = *(const float4*)&xq[nd * 68 + 4 * v];
                float o00 = xu.y * xv.y, o01 = xu.y * xv.z, o02 = xu.y * xv.w;
                float o10 = xu.z * xv.y, o11 = xu.z * xv.z, o12 = xu.z * xv.w;
                float o20 = xu.w * xv.y, o21 = xu.w * xv.z, o22 = xu.w * xv.w;
                float s1 = (o00 + o11) + o22;
                tf[0][e] = o01 + o10;
                tf[1][e] = o02 + o20;
                tf[2][e] = o12 + o21;
                tf[3][e] = o00 - o11;
                tf[4][e] = SQ3 * o22 - ISQ3 * s1;
            } else {
#pragma unroll
                for (int k = 0; k < 5; ++k) tf[k][e] = 0.f;
            }
        }
        int o = nd * SSTR + 2 * pi;
#pragma unroll
        for (int k = 0; k < 5; ++k)
            *(bf16x2*)&tbuf[b][k][o] = (bf16x2){(__bf16)tf[k][0], (__bf16)tf[k][1]};
    };

    const int lane = tid & 63;
    const int wid  = __builtin_amdgcn_readfirstlane(tid >> 6);
    const int m = lane & 15, q = lane >> 4;
    const int kk = wid - 1;
    const bf16x8* wb = (const bf16x8*)wtiles;

    f32x4 accA = {0.f, 0.f, 0.f, 0.f};
    f32x4 accB = {0.f, 0.f, 0.f, 0.f};
    f32x4 accC = {0.f, 0.f, 0.f, 0.f};

    // ---- s + pq pipeline: 9 chunks ----
    computeSP(0, 0);
    __syncthreads();
    for (int c = 0; c < 9; ++c) {
        if (c < 8) computeSP(c + 1, (c + 1) & 1);
        int b = c & 1;
        if (wid == 0) {
            accA = __builtin_amdgcn_mfma_f32_16x16x32_bf16(
                *(const bf16x8*)&sbuf[b][m * SSTR + 8 * q],
                wb[c * 64 + lane], accA, 0, 0, 0);
        } else {
            accA = __builtin_amdgcn_mfma_f32_16x16x32_bf16(
                *(const bf16x8*)&pqbuf[b][kk][m * SSTR + 8 * q],
                wb[(9 + c) * 64 + lane], accA, 0, 0, 0);
        }
        __syncthreads();
    }

    // ---- t pipeline: 5 chunks ----
    computeT(0, 0);
    __syncthreads();
    for (int c = 0; c < 5; ++c) {
        if (c < 4) computeT(c + 1, (c + 1) & 1);
        int b = c & 1;
        bf16x8 bt = wb[(18 + c) * 64 + lane];
        if (wid == 0) {
            accB = __builtin_amdgcn_mfma_f32_16x16x32_bf16(
                *(const bf16x8*)&tbuf[b][3][m * SSTR + 8 * q], bt, accB, 0, 0, 0);
            accC = __builtin_amdgcn_mfma_f32_16x16x32_bf16(
                *(const bf16x8*)&tbuf[b][4][m * SSTR + 8 * q], bt, accC, 0, 0, 0);
        } else {
            accB = __builtin_amdgcn_mfma_f32_16x16x32_bf16(
                *(const bf16x8*)&tbuf[b][kk][m * SSTR + 8 * q], bt, accB, 0, 0, 0);
        }
        __syncthreads();
    }

    // ---- epilogue: C/D col = lane&15 = output idx w, row = q*4+r = node ----
    const int w = m;
    if (wid == 0) {
#pragma unroll
        for (int r = 0; r < 4; ++r) {
            int ndo = q * 4 + r;
            float* ob = out + (blockNode + ndo) * 144;
            ob[w]              = accA[r];
            ob[64 + 5 * w + 3] = accB[r];
            ob[64 + 5 * w + 4] = accC[r];
        }
    } else {
#pragma unroll
        for (int r = 0; r < 4; ++r) {
            int ndo = q * 4 + r;
            float* ob = out + (blockNode + ndo) * 144;
            ob[16 + 3 * w + kk] = accA[r];
            ob[64 + 5 * w + kk] = accB[r];
        }
    }
}

extern "C" void kernel_launch(void* const* d_in, const int* in_sizes, int n_in,
                              void* d_out, int out_size, void* d_ws, size_t ws_size,
                              hipStream_t stream) {
    const float* feats = (const float*)d_in[0];
    const float* msgs  = (const float*)d_in[1];
    const float* w000  = (const float*)d_in[2];
    const float* w101  = (const float*)d_in[3];
    const float* w110  = (const float*)d_in[4];
    const float* w112  = (const float*)d_in[5];
    __bf16* wt = (__bf16*)d_ws;
    float* out = (float*)d_out;

    const int n = in_sizes[0] / (4 * MUL);   // 131072 nodes

    prep_weights<<<1, 256, 0, stream>>>(w000, w101, w110, w112, wt);
    tsq_kernel<<<n / NPB, 256, 0, stream>>>(feats, msgs, wt, out);
}